// Round 6
// baseline (82.584 us; speedup 1.0000x reference)
//
#include <hip/hip_runtime.h>
#include <hip/hip_bf16.h>

#define CORR_STRENGTH 0.1f
#define ERR_THRESH2 1e-12f   // (1e-6)^2 : norm(s) > 1e-6  <=>  |s|^2 > 1e-12

typedef float floatx4 __attribute__((ext_vector_type(4)));

// QEC update for one 3-float block.
__device__ __forceinline__ void qec_block(
    const float* __restrict__ ws, const float* __restrict__ bs,
    const float* __restrict__ wc, const float* __restrict__ bc,
    float x0, float x1, float x2, float* __restrict__ y)
{
    float s[3];
#pragma unroll
    for (int k = 0; k < 3; ++k)
        s[k] = fmaf(ws[k * 3 + 0], x0,
                fmaf(ws[k * 3 + 1], x1,
                 fmaf(ws[k * 3 + 2], x2, bs[k])));

    const float mag2 = s[0] * s[0] + s[1] * s[1] + s[2] * s[2];
    const bool active = mag2 > ERR_THRESH2;

    float corr[3] = {0.f, 0.f, 0.f};
#pragma unroll
    for (int j = 0; j < 3; ++j) {
#pragma unroll
        for (int k = 0; k < 3; ++k) {
            const float co = fmaf(wc[j * 9 + k * 3 + 0], x0,
                              fmaf(wc[j * 9 + k * 3 + 1], x1,
                               fmaf(wc[j * 9 + k * 3 + 2], x2, bc[j * 3 + k])));
            corr[k] = fmaf(s[j], co, corr[k]);
        }
    }

    y[0] = active ? (x0 - CORR_STRENGTH * corr[0]) : x0;
    y[1] = active ? (x1 - CORR_STRENGTH * corr[1]) : x1;
    y[2] = active ? (x2 - CORR_STRENGTH * corr[2]) : x2;
}

__global__ void __launch_bounds__(256) qec_kernel(
    const float* __restrict__ params,
    const float* __restrict__ Wsyn,   // [3][3]
    const float* __restrict__ bsyn,   // [3]
    const float* __restrict__ Wcorr,  // [3][3][3]
    const float* __restrict__ bcorr,  // [3][3]
    float* __restrict__ out,
    long long ngrp,                   // 48-float groups (12 float4 each)
    long long nvec,                   // total 12-float chunks
    long long nblk)                   // total 3-float blocks
{
    // Tiny weights: uniform addresses -> scalar loads, cached.
    float ws[9], bs[3], wc[27], bc[9];
#pragma unroll
    for (int i = 0; i < 9; ++i)  ws[i] = Wsyn[i];
#pragma unroll
    for (int i = 0; i < 3; ++i)  bs[i] = bsyn[i];
#pragma unroll
    for (int i = 0; i < 27; ++i) wc[i] = Wcorr[i];
#pragma unroll
    for (int i = 0; i < 9; ++i)  bc[i] = bcorr[i];

    const long long tid     = (long long)blockIdx.x * blockDim.x + threadIdx.x;
    const long long nthread = (long long)gridDim.x * blockDim.x;

    const floatx4* __restrict__ src4 = reinterpret_cast<const floatx4*>(params);
    floatx4* __restrict__       dst4 = reinterpret_cast<floatx4*>(out);

    // ---- Main path: each thread owns one 192B group = 12 float4.
    // All 12 loads are independent and issued before any compute -> 12
    // outstanding vector loads per lane (max MLP). Grid sized for exactly
    // one group per thread; loop kept for safety.
    for (long long g = tid; g < ngrp; g += nthread) {
        const long long b = g * 12;
        floatx4 v[12];
#pragma unroll
        for (int i = 0; i < 12; ++i) v[i] = src4[b + i];

        float y[48];
#pragma unroll
        for (int q = 0; q < 4; ++q) {
            float x[12] = { v[q*3+0].x, v[q*3+0].y, v[q*3+0].z, v[q*3+0].w,
                            v[q*3+1].x, v[q*3+1].y, v[q*3+1].z, v[q*3+1].w,
                            v[q*3+2].x, v[q*3+2].y, v[q*3+2].z, v[q*3+2].w };
#pragma unroll
            for (int bl = 0; bl < 4; ++bl)
                qec_block(ws, bs, wc, bc,
                          x[bl*3+0], x[bl*3+1], x[bl*3+2],
                          &y[q*12 + bl*3]);
        }

#pragma unroll
        for (int i = 0; i < 12; ++i) {
            floatx4 o = { y[i*4+0], y[i*4+1], y[i*4+2], y[i*4+3] };
            dst4[b + i] = o;
        }
    }

    // ---- Tails ----
    // Leftover 12-float chunks beyond the groups.
    const long long tailIdx0 = ngrp * 4;
    for (long long idx = tailIdx0 + tid; idx < nvec; idx += nthread) {
        floatx4 a = src4[idx * 3 + 0];
        floatx4 bb = src4[idx * 3 + 1];
        floatx4 c = src4[idx * 3 + 2];
        float x[12] = { a.x, a.y, a.z, a.w,
                        bb.x, bb.y, bb.z, bb.w,
                        c.x, c.y, c.z, c.w };
        float y[12];
#pragma unroll
        for (int bl = 0; bl < 4; ++bl)
            qec_block(ws, bs, wc, bc,
                      x[bl*3+0], x[bl*3+1], x[bl*3+2], &y[bl*3]);
        dst4[idx * 3 + 0] = floatx4{ y[0], y[1], y[2],  y[3]  };
        dst4[idx * 3 + 1] = floatx4{ y[4], y[5], y[6],  y[7]  };
        dst4[idx * 3 + 2] = floatx4{ y[8], y[9], y[10], y[11] };
    }

    // Leftover 3-float blocks (scalar path).
    const long long firstTailBlk = nvec * 4;
    for (long long blk = firstTailBlk + tid; blk < nblk; blk += nthread) {
        float y[3];
        qec_block(ws, bs, wc, bc,
                  params[blk*3+0], params[blk*3+1], params[blk*3+2], y);
        out[blk*3+0] = y[0];
        out[blk*3+1] = y[1];
        out[blk*3+2] = y[2];
    }
}

extern "C" void kernel_launch(void* const* d_in, const int* in_sizes, int n_in,
                              void* d_out, int out_size, void* d_ws, size_t ws_size,
                              hipStream_t stream) {
    const float* params = (const float*)d_in[0];
    const float* Wsyn   = (const float*)d_in[1];
    const float* bsyn   = (const float*)d_in[2];
    const float* Wcorr  = (const float*)d_in[3];
    const float* bcorr  = (const float*)d_in[4];
    float* out = (float*)d_out;

    const long long n    = (long long)in_sizes[0];  // total elements
    const long long nblk = n / 3;                   // 3-float blocks
    const long long nvec = n / 12;                  // 12-float chunks
    const long long ngrp = n / 48;                  // 48-float groups

    const int block = 256;
    // One group per thread: ngrp = 524,288 -> 2048 blocks of 256.
    long long grid_ll = (ngrp + block - 1) / block;
    if (grid_ll < 1) grid_ll = 1;
    if (grid_ll > 16384) grid_ll = 16384;
    const int grid = (int)grid_ll;

    qec_kernel<<<grid, block, 0, stream>>>(params, Wsyn, bsyn, Wcorr, bcorr,
                                           out, ngrp, nvec, nblk);
}

// Round 7
// 38.006 us; speedup vs baseline: 2.1729x; 2.1729x over previous
//
#include <hip/hip_runtime.h>
#include <hip/hip_bf16.h>

#define CORR_STRENGTH 0.1f
#define ERR_THRESH2 1e-12f   // (1e-6)^2 : norm(s) > 1e-6  <=>  |s|^2 > 1e-12

typedef float floatx4 __attribute__((ext_vector_type(4)));

// Computes the QEC update for one 3-float block.
__device__ __forceinline__ void qec_block(
    const float* __restrict__ ws, const float* __restrict__ bs,
    const float* __restrict__ wc, const float* __restrict__ bc,
    float x0, float x1, float x2, float* __restrict__ y)
{
    float s[3];
#pragma unroll
    for (int k = 0; k < 3; ++k)
        s[k] = fmaf(ws[k * 3 + 0], x0,
                fmaf(ws[k * 3 + 1], x1,
                 fmaf(ws[k * 3 + 2], x2, bs[k])));

    const float mag2 = s[0] * s[0] + s[1] * s[1] + s[2] * s[2];
    const bool active = mag2 > ERR_THRESH2;

    float corr[3] = {0.f, 0.f, 0.f};
#pragma unroll
    for (int j = 0; j < 3; ++j) {
#pragma unroll
        for (int k = 0; k < 3; ++k) {
            const float co = fmaf(wc[j * 9 + k * 3 + 0], x0,
                              fmaf(wc[j * 9 + k * 3 + 1], x1,
                               fmaf(wc[j * 9 + k * 3 + 2], x2, bc[j * 3 + k])));
            corr[k] = fmaf(s[j], co, corr[k]);
        }
    }

    y[0] = active ? (x0 - CORR_STRENGTH * corr[0]) : x0;
    y[1] = active ? (x1 - CORR_STRENGTH * corr[1]) : x1;
    y[2] = active ? (x2 - CORR_STRENGTH * corr[2]) : x2;
}

__global__ void __launch_bounds__(256) qec_kernel(
    const float* __restrict__ params,
    const float* __restrict__ Wsyn,   // [3][3]
    const float* __restrict__ bsyn,   // [3]
    const float* __restrict__ Wcorr,  // [3][3][3]
    const float* __restrict__ bcorr,  // [3][3]
    float* __restrict__ out,
    long long nBT,                    // full block-tiles (768 float4 each)
    long long nvec,                   // total 12-float (3-float4) chunks
    long long nblk)                   // total 3-float blocks
{
    // Wave-private staging: 4 waves x 192 float4 (3 KB each).
    __shared__ floatx4 lds[4][192];

    // Tiny weights: uniform addresses -> scalar loads, cached.
    float ws[9], bs[3], wc[27], bc[9];
#pragma unroll
    for (int i = 0; i < 9; ++i)  ws[i] = Wsyn[i];
#pragma unroll
    for (int i = 0; i < 3; ++i)  bs[i] = bsyn[i];
#pragma unroll
    for (int i = 0; i < 27; ++i) wc[i] = Wcorr[i];
#pragma unroll
    for (int i = 0; i < 9; ++i)  bc[i] = bcorr[i];

    const int wave = threadIdx.x >> 6;
    const int lane = threadIdx.x & 63;

    const floatx4* __restrict__ src4 = reinterpret_cast<const floatx4*>(params);
    floatx4* __restrict__       dst4 = reinterpret_cast<floatx4*>(out);

    // ---- Main coalesced path: one block-tile = 768 contiguous float4 ----
    // Per wave: 3 fully-coalesced 1KB loads -> LDS -> per-lane contiguous
    // 48B reads (stride-48B b128 is bank-conflict-free: 8 lanes x 12-bank
    // step cover all 32 banks) -> compute -> reverse permutation -> 3
    // coalesced 1KB stores.
    for (long long bt = blockIdx.x; bt < nBT; bt += gridDim.x) {
        const long long base4 = bt * 768 + (long long)wave * 192;

        floatx4 v0 = src4[base4 +   0 + lane];
        floatx4 v1 = src4[base4 +  64 + lane];
        floatx4 v2 = src4[base4 + 128 + lane];
        lds[wave][  0 + lane] = v0;
        lds[wave][ 64 + lane] = v1;
        lds[wave][128 + lane] = v2;
        __syncthreads();

        floatx4 a = lds[wave][3 * lane + 0];
        floatx4 b = lds[wave][3 * lane + 1];
        floatx4 c = lds[wave][3 * lane + 2];

        float x[12] = { a.x, a.y, a.z, a.w,
                        b.x, b.y, b.z, b.w,
                        c.x, c.y, c.z, c.w };
        float y[12];
#pragma unroll
        for (int bl = 0; bl < 4; ++bl)
            qec_block(ws, bs, wc, bc,
                      x[bl * 3 + 0], x[bl * 3 + 1], x[bl * 3 + 2],
                      &y[bl * 3]);

        floatx4 o0 = { y[0], y[1], y[2],  y[3]  };
        floatx4 o1 = { y[4], y[5], y[6],  y[7]  };
        floatx4 o2 = { y[8], y[9], y[10], y[11] };
        __syncthreads();   // WAR: don't overwrite until all reads done
        lds[wave][3 * lane + 0] = o0;
        lds[wave][3 * lane + 1] = o1;
        lds[wave][3 * lane + 2] = o2;
        __syncthreads();

        floatx4 r0 = lds[wave][  0 + lane];
        floatx4 r1 = lds[wave][ 64 + lane];
        floatx4 r2 = lds[wave][128 + lane];
        dst4[base4 +   0 + lane] = r0;
        dst4[base4 +  64 + lane] = r1;
        dst4[base4 + 128 + lane] = r2;
        __syncthreads();   // WAR before next iteration's stage-in
    }

    // ---- Tail paths (no barriers; remainder only) ----
    const long long tid     = (long long)blockIdx.x * blockDim.x + threadIdx.x;
    const long long nthread = (long long)gridDim.x * blockDim.x;

    // Leftover 12-float chunks beyond the block-tiles (old strided path).
    const long long tailIdx0 = nBT * 256;
    for (long long idx = tailIdx0 + tid; idx < nvec; idx += nthread) {
        floatx4 a = src4[idx * 3 + 0];
        floatx4 b = src4[idx * 3 + 1];
        floatx4 c = src4[idx * 3 + 2];
        float x[12] = { a.x, a.y, a.z, a.w,
                        b.x, b.y, b.z, b.w,
                        c.x, c.y, c.z, c.w };
        float y[12];
#pragma unroll
        for (int bl = 0; bl < 4; ++bl)
            qec_block(ws, bs, wc, bc,
                      x[bl * 3 + 0], x[bl * 3 + 1], x[bl * 3 + 2],
                      &y[bl * 3]);
        dst4[idx * 3 + 0] = floatx4{ y[0], y[1], y[2],  y[3]  };
        dst4[idx * 3 + 1] = floatx4{ y[4], y[5], y[6],  y[7]  };
        dst4[idx * 3 + 2] = floatx4{ y[8], y[9], y[10], y[11] };
    }

    // Leftover 3-float blocks beyond nvec*4 (scalar path).
    const long long firstTailBlk = nvec * 4;
    for (long long blk = firstTailBlk + tid; blk < nblk; blk += nthread) {
        float y[3];
        qec_block(ws, bs, wc, bc,
                  params[blk * 3 + 0], params[blk * 3 + 1], params[blk * 3 + 2], y);
        out[blk * 3 + 0] = y[0];
        out[blk * 3 + 1] = y[1];
        out[blk * 3 + 2] = y[2];
    }
}

extern "C" void kernel_launch(void* const* d_in, const int* in_sizes, int n_in,
                              void* d_out, int out_size, void* d_ws, size_t ws_size,
                              hipStream_t stream) {
    const float* params = (const float*)d_in[0];
    const float* Wsyn   = (const float*)d_in[1];
    const float* bsyn   = (const float*)d_in[2];
    const float* Wcorr  = (const float*)d_in[3];
    const float* bcorr  = (const float*)d_in[4];
    float* out = (float*)d_out;

    const long long n     = (long long)in_sizes[0];  // total elements
    const long long nblk  = n / 3;                   // 3-float blocks
    const long long nvec  = n / 12;                  // 12-float chunks
    const long long nf4   = n / 4;                   // aligned float4 count
    const long long nBT   = nf4 / 768;               // block-tiles (768 f4 each)

    const int block = 256;
    long long grid_ll = nBT > 0 ? nBT : 1;
    if (grid_ll > 16384) grid_ll = 16384;
    const int grid = (int)grid_ll;   // 8192 for the bench shape: 1 tile/block

    qec_kernel<<<grid, block, 0, stream>>>(params, Wsyn, bsyn, Wcorr, bcorr,
                                           out, nBT, nvec, nblk);
}